// Round 1
// baseline (867.843 us; speedup 1.0000x reference)
//
#include <hip/hip_runtime.h>

typedef __attribute__((ext_vector_type(8))) short short8;
typedef __attribute__((ext_vector_type(8))) unsigned short ushort8;
typedef __attribute__((ext_vector_type(4))) unsigned short ushort4_t;
typedef __attribute__((ext_vector_type(4))) float floatx4;

#define NUM_AUTHORS 200000
#define HID 128
#define ABITS 9   // 512 authors per bucket
#define NB 391    // ceil(200000 / 512)
#define CHUNK 8192

__device__ __forceinline__ unsigned short f32_to_bf16(float f) {
  union { float f; unsigned int u; } v; v.f = f;
  unsigned int u = v.u;
  u += 0x7FFF + ((u >> 16) & 1);   // round-to-nearest-even
  return (unsigned short)(u >> 16);
}
__device__ __forceinline__ float bf16_to_f32(unsigned short h) {
  union { unsigned int u; float f; } v; v.u = ((unsigned int)h) << 16; return v.f;
}

// W[128][128] fp32 -> fragment-ordered bf16 image for MFMA "A" operand.
// Fragment f = tt*4+ks (tt = 16-col tile of output cols, ks = K/32 slice).
// Unit index idx = f*64 + lane; lane holds outcol = tt*16+(lane&15),
// k = ks*32+(lane>>4)*8 + j, j=0..7.  Wfrag[idx*8 + j] = bf16(W[k][outcol]).
__global__ __launch_bounds__(256) void prep_w(
    const float* __restrict__ Wp, const float* __restrict__ Wa,
    unsigned short* __restrict__ WtP, unsigned short* __restrict__ WtA)
{
  const float* W = blockIdx.x ? Wa : Wp;
  unsigned short* Wt = blockIdx.x ? WtA : WtP;
  int t = threadIdx.x;
#pragma unroll
  for (int i = 0; i < 8; ++i) {
    int idx = i * 256 + t;          // 0..2047
    int f = idx >> 6;
    int lane = idx & 63;
    int tt = f >> 2, ks = f & 3;
    int m = lane & 15, q = lane >> 4;
    int col = tt * 16 + m;
    int kb = ks * 32 + q * 8;
    ushort8 h;
#pragma unroll
    for (int j = 0; j < 8; ++j) h[j] = f32_to_bf16(W[(size_t)(kb + j) * HID + col]);
    *(ushort8*)&Wt[(size_t)idx * 8] = h;
  }
}

// Y[M,128](bf16) = rowscale(X[M,128]) @ W[128,128] + bias
// Barrier-free: W fragments staged to LDS once; each wave grid-strides over
// private 16-row tiles, X fragments loaded global->reg, MFMA with swapped
// operands (A=W frag rows=outcols, B=X frag cols=papers) so each lane holds
// 4 consecutive output columns -> 8B stores.
template<bool X_IS_BF16>
__global__ __launch_bounds__(256, 4) void gemm_mfma(
    const void* __restrict__ Xv, const unsigned short* __restrict__ Wfrag,
    const float* __restrict__ bias, const int* __restrict__ counts,
    unsigned short* __restrict__ Y, int M)
{
  __shared__ unsigned short Bs[32 * 64 * 8];   // 32 KB, fragment-ordered
  const int t = threadIdx.x;
#pragma unroll
  for (int i = 0; i < 8; ++i) {
    int g = i * 256 + t;
    *(ushort8*)&Bs[(size_t)g * 8] = *(const ushort8*)&Wfrag[(size_t)g * 8];
  }
  __syncthreads();

  const int w = t >> 6;
  const int lane = t & 63;
  const int m = lane & 15;
  const int q = lane >> 4;

  const int nTiles = (M + 15) >> 4;
  const int waveId = blockIdx.x * 4 + w;
  const int nWaves = gridDim.x * 4;

  for (int tile = waveId; tile < nTiles; tile += nWaves) {
    const int p = tile * 16 + m;           // this lane's input row (paper/author)
    const bool valid = (p < M);

    // X fragments: lane holds X[p][ks*32 + q*8 .. +8] for ks=0..3
    short8 xf[4];
    if (X_IS_BF16) {
      const unsigned short* X = (const unsigned short*)Xv;
      const unsigned short* xp = X + (size_t)p * HID + q * 8;
#pragma unroll
      for (int ks = 0; ks < 4; ++ks) {
        if (valid) xf[ks] = *(const short8*)(xp + ks * 32);
        else       xf[ks] = (short8)0;
      }
    } else {
      const float* X = (const float*)Xv;
      const float* xp = X + (size_t)p * HID + q * 8;
#pragma unroll
      for (int ks = 0; ks < 4; ++ks) {
        float4 a0, a1;
        if (valid) {
          a0 = *(const float4*)(xp + ks * 32);
          a1 = *(const float4*)(xp + ks * 32 + 4);
        } else {
          a0 = make_float4(0.f, 0.f, 0.f, 0.f); a1 = a0;
        }
        short8 h;
        h[0] = (short)f32_to_bf16(a0.x); h[1] = (short)f32_to_bf16(a0.y);
        h[2] = (short)f32_to_bf16(a0.z); h[3] = (short)f32_to_bf16(a0.w);
        h[4] = (short)f32_to_bf16(a1.x); h[5] = (short)f32_to_bf16(a1.y);
        h[6] = (short)f32_to_bf16(a1.z); h[7] = (short)f32_to_bf16(a1.w);
        xf[ks] = h;
      }
    }

    floatx4 acc[8];
#pragma unroll
    for (int tt = 0; tt < 8; ++tt) acc[tt] = (floatx4)(0.f);

#pragma unroll
    for (int ks = 0; ks < 4; ++ks) {
#pragma unroll
      for (int tt = 0; tt < 8; ++tt) {
        short8 wf = *(const short8*)&Bs[(size_t)((tt * 4 + ks) * 64 + lane) * 8];
        acc[tt] = __builtin_amdgcn_mfma_f32_16x16x32_bf16(wf, xf[ks], acc[tt], 0, 0, 0);
      }
    }

    float inv = 1.0f;
    if (counts) {
      float c = valid ? (float)counts[p] : 1.0f;
      inv = 1.0f / fmaxf(c, 1.0f);
    }

    if (valid) {
      unsigned short* yp = Y + (size_t)p * HID + q * 4;
#pragma unroll
      for (int tt = 0; tt < 8; ++tt) {
        const float4 bv = *(const float4*)(bias + tt * 16 + q * 4);
        ushort4_t o;
        o[0] = f32_to_bf16(acc[tt][0] * inv + bv.x);
        o[1] = f32_to_bf16(acc[tt][1] * inv + bv.y);
        o[2] = f32_to_bf16(acc[tt][2] * inv + bv.z);
        o[3] = f32_to_bf16(acc[tt][3] * inv + bv.w);
        *(ushort4_t*)(yp + tt * 16) = o;
      }
    }
  }
}

// ---- author-count histogram + scan (for offsets/cnt) ----
__global__ __launch_bounds__(256) void hist_kernel(
    const int* __restrict__ aid, int* __restrict__ cnt, int n)
{
  int i = blockIdx.x * 256 + threadIdx.x;
  if (i < n) atomicAdd(&cnt[aid[i]], 1);
}

__global__ __launch_bounds__(256) void scan1(
    const int* __restrict__ cnt, int* __restrict__ offsets,
    int* __restrict__ blockSums, int n)
{
  __shared__ int s[256];
  int t = threadIdx.x;
  int i = blockIdx.x * 256 + t;
  int v = (i < n) ? cnt[i] : 0;
  s[t] = v; __syncthreads();
#pragma unroll
  for (int off = 1; off < 256; off <<= 1) {
    int tv = 0;
    if (t >= off) tv = s[t - off];
    __syncthreads();
    if (t >= off) s[t] += tv;
    __syncthreads();
  }
  if (i < n) offsets[i] = s[t] - v;
  if (t == 255) blockSums[blockIdx.x] = s[255];
}

__global__ __launch_bounds__(1024) void scan2(int* __restrict__ blockSums, int nb)
{
  __shared__ int s[1024];
  int t = threadIdx.x;
  int v = (t < nb) ? blockSums[t] : 0;
  s[t] = v; __syncthreads();
#pragma unroll
  for (int off = 1; off < 1024; off <<= 1) {
    int tv = 0;
    if (t >= off) tv = s[t - off];
    __syncthreads();
    if (t >= off) s[t] += tv;
    __syncthreads();
  }
  if (t < nb) blockSums[t] = s[t] - v;
}

__global__ __launch_bounds__(256) void scan3(
    int* __restrict__ offsets, const int* __restrict__ blockSums, int n)
{
  int i = blockIdx.x * 256 + threadIdx.x;
  if (i < n) offsets[i] += blockSums[blockIdx.x];
}

// ---- two-level radix partition ----
__global__ __launch_bounds__(256) void bucket_hist(
    const int* __restrict__ aid, int* __restrict__ bcnt, int n)
{
  __shared__ int hist[NB];
  int t = threadIdx.x;
  for (int i = t; i < NB; i += 256) hist[i] = 0;
  __syncthreads();
  int e0 = blockIdx.x * CHUNK;
  int e1 = min(e0 + CHUNK, n);
  for (int e = e0 + t; e < e1; e += 256) atomicAdd(&hist[aid[e] >> ABITS], 1);
  __syncthreads();
  for (int i = t; i < NB; i += 256) {
    int h = hist[i];
    if (h) atomicAdd(&bcnt[i], h);
  }
}

__global__ __launch_bounds__(512) void bucket_scan(
    const int* __restrict__ bcnt, int* __restrict__ boff, int* __restrict__ bcur, int n)
{
  __shared__ int s[512];
  int t = threadIdx.x;
  int v = (t < NB) ? bcnt[t] : 0;
  s[t] = v; __syncthreads();
#pragma unroll
  for (int off = 1; off < 512; off <<= 1) {
    int tv = 0;
    if (t >= off) tv = s[t - off];
    __syncthreads();
    if (t >= off) s[t] += tv;
    __syncthreads();
  }
  if (t < NB) { int e = s[t] - v; boff[t] = e; bcur[t] = e; }
  if (t == 0) boff[NB] = n;
}

__global__ __launch_bounds__(256) void partA(
    const int* __restrict__ aid, const int* __restrict__ pid,
    int* __restrict__ bcur, uint2* __restrict__ pairs, int n)
{
  __shared__ int hist[NB];
  __shared__ int cur[NB];
  int t = threadIdx.x;
  for (int i = t; i < NB; i += 256) hist[i] = 0;
  __syncthreads();
  int e0 = blockIdx.x * CHUNK;
  int e1 = min(e0 + CHUNK, n);
  for (int e = e0 + t; e < e1; e += 256) atomicAdd(&hist[aid[e] >> ABITS], 1);
  __syncthreads();
  for (int i = t; i < NB; i += 256) {
    int h = hist[i];
    cur[i] = h ? atomicAdd(&bcur[i], h) : 0;
  }
  __syncthreads();
  for (int e = e0 + t; e < e1; e += 256) {
    int a = aid[e];
    int pos = atomicAdd(&cur[a >> ABITS], 1);
    pairs[pos] = make_uint2((unsigned)a, (unsigned)pid[e]);
  }
}

__global__ __launch_bounds__(256) void partB(
    const uint2* __restrict__ pairs, const int* __restrict__ boff,
    const int* __restrict__ offsets, int* __restrict__ csr)
{
  __shared__ int lcur[1 << ABITS];
  int b = blockIdx.x;
  int t = threadIdx.x;
  int a0 = b << ABITS;
  for (int i = t; i < (1 << ABITS); i += 256) {
    int g = a0 + i;
    lcur[i] = (g < NUM_AUTHORS) ? offsets[g] : 0;
  }
  __syncthreads();
  int s = boff[b], e = boff[b + 1];
  for (int i = s + t; i < e; i += 256) {
    uint2 pr = pairs[i];
    int pos = atomicAdd(&lcur[pr.x - a0], 1);
    csr[pos] = (int)pr.y;
  }
}

// One wave per author; 4x16-lane groups each gather one 256B row per iter.
__global__ __launch_bounds__(256) void accumulate_kernel(
    const unsigned short* __restrict__ paper_hb, const int* __restrict__ csr,
    const int* __restrict__ offsets, const int* __restrict__ cnt,
    unsigned short* __restrict__ author_in)
{
  int a = blockIdx.x * 4 + (threadIdx.x >> 6);
  if (a >= NUM_AUTHORS) return;
  int lane = threadIdx.x & 63;
  int sub = lane >> 4;
  int c16 = lane & 15;
  int start = offsets[a];
  int n = cnt[a];
  float acc[8];
#pragma unroll
  for (int j = 0; j < 8; ++j) acc[j] = 0.f;
  for (int i = 0; i < n; i += 4) {
    int idx = i + sub;
    if (idx < n) {
      int p = csr[start + idx];
      ushort8 h = *(const ushort8*)(paper_hb + (size_t)p * HID + c16 * 8);
#pragma unroll
      for (int j = 0; j < 8; ++j) acc[j] += bf16_to_f32(h[j]);
    }
  }
#pragma unroll
  for (int j = 0; j < 8; ++j) {
    acc[j] += __shfl_xor(acc[j], 16, 64);
    acc[j] += __shfl_xor(acc[j], 32, 64);
  }
  if (sub == 0) {
    ushort8 o;
#pragma unroll
    for (int j = 0; j < 8; ++j) o[j] = f32_to_bf16(acc[j]);
    *(ushort8*)(author_in + (size_t)a * HID + c16 * 8) = o;
  }
}

// One edge per 16-lane group; 16B loads/lane.
__global__ __launch_bounds__(256) void dot_kernel(
    const unsigned short* __restrict__ author_hb, const unsigned short* __restrict__ paper_hb,
    const int* __restrict__ la, const int* __restrict__ lp,
    float* __restrict__ out, int n)
{
  int e = blockIdx.x * 16 + (threadIdx.x >> 4);
  if (e >= n) return;
  int c16 = threadIdx.x & 15;
  int a = la[e], p = lp[e];
  ushort8 ah = *(const ushort8*)(author_hb + (size_t)a * HID + c16 * 8);
  ushort8 ph = *(const ushort8*)(paper_hb + (size_t)p * HID + c16 * 8);
  float s = 0.f;
#pragma unroll
  for (int j = 0; j < 8; ++j) s += bf16_to_f32(ah[j]) * bf16_to_f32(ph[j]);
  s += __shfl_xor(s, 1, 64);
  s += __shfl_xor(s, 2, 64);
  s += __shfl_xor(s, 4, 64);
  s += __shfl_xor(s, 8, 64);
  if (c16 == 0) out[e] = s;
}

extern "C" void kernel_launch(void* const* d_in, const int* in_sizes, int n_in,
                              void* d_out, int out_size, void* d_ws, size_t ws_size,
                              hipStream_t stream)
{
  const float* paper_x          = (const float*)d_in[0];
  const int*   author_ids       = (const int*)d_in[1];
  const int*   paper_ids        = (const int*)d_in[2];
  const int*   label_author_ids = (const int*)d_in[3];
  const int*   label_paper_ids  = (const int*)d_in[4];
  const float* W_paper          = (const float*)d_in[5];
  const float* b_paper          = (const float*)d_in[6];
  const float* W_author         = (const float*)d_in[7];
  const float* b_author         = (const float*)d_in[8];
  float* out = (float*)d_out;

  const int num_papers = in_sizes[0] / HID;
  const int num_edges  = in_sizes[1];
  const int num_label  = in_sizes[3];
  const int NA = NUM_AUTHORS;

  char* ws = (char*)d_ws;
  size_t off = 0;
  auto alloc = [&](size_t bytes) { void* p = ws + off; off = (off + bytes + 255) & ~(size_t)255; return p; };
  unsigned short* paper_hb  = (unsigned short*)alloc((size_t)num_papers * HID * 2);
  unsigned short* author_in = (unsigned short*)alloc((size_t)NA * HID * 2);
  unsigned short* author_hb = (unsigned short*)alloc((size_t)NA * HID * 2);
  int* counts_int = (int*)alloc((size_t)NA * 4);
  int* bcnt       = (int*)alloc((size_t)(NB + 1) * 4);
  int* boff       = (int*)alloc((size_t)(NB + 1) * 4);
  int* bcur       = (int*)alloc((size_t)NB * 4);
  int* offsets    = (int*)alloc((size_t)NA * 4);
  int* blockSums  = (int*)alloc(1024 * 4);
  int* csr        = (int*)alloc((size_t)num_edges * 4);
  uint2* pairs    = (uint2*)alloc((size_t)num_edges * 8);
  unsigned short* WtP = (unsigned short*)alloc(HID * HID * 2);
  unsigned short* WtA = (unsigned short*)alloc(HID * HID * 2);

  hipMemsetAsync(counts_int, 0, (size_t)NA * 4, stream);
  hipMemsetAsync(bcnt, 0, (size_t)(NB + 1) * 4, stream);

  prep_w<<<2, 256, 0, stream>>>(W_paper, W_author, WtP, WtA);

  // paper GEMM: 31250 tiles of 16 rows; ~8 tiles/wave
  {
    const int nTiles = (num_papers + 15) / 16;
    const int blocks = (nTiles + 8 * 4 - 1) / (8 * 4);
    gemm_mfma<false><<<blocks, 256, 0, stream>>>(
        paper_x, WtP, b_paper, nullptr, paper_hb, num_papers);
  }

  hist_kernel<<<(num_edges + 255) / 256, 256, 0, stream>>>(author_ids, counts_int, num_edges);

  const int nb = (NA + 255) / 256;   // 782 <= 1024
  scan1<<<nb, 256, 0, stream>>>(counts_int, offsets, blockSums, NA);
  scan2<<<1, 1024, 0, stream>>>(blockSums, nb);
  scan3<<<nb, 256, 0, stream>>>(offsets, blockSums, NA);

  const int nchunks = (num_edges + CHUNK - 1) / CHUNK;
  bucket_hist<<<nchunks, 256, 0, stream>>>(author_ids, bcnt, num_edges);
  bucket_scan<<<1, 512, 0, stream>>>(bcnt, boff, bcur, num_edges);
  partA<<<nchunks, 256, 0, stream>>>(author_ids, paper_ids, bcur, pairs, num_edges);
  partB<<<NB, 256, 0, stream>>>(pairs, boff, offsets, csr);

  accumulate_kernel<<<(NA + 3) / 4, 256, 0, stream>>>(
      paper_hb, csr, offsets, counts_int, author_in);

  // author GEMM: 12500 tiles; ~4 tiles/wave
  {
    const int nTiles = (NA + 15) / 16;
    const int blocks = (nTiles + 4 * 4 - 1) / (4 * 4);
    gemm_mfma<true><<<blocks, 256, 0, stream>>>(
        author_in, WtA, b_author, counts_int, author_hb, NA);
  }

  dot_kernel<<<(num_label + 15) / 16, 256, 0, stream>>>(
      author_hb, paper_hb, label_author_ids, label_paper_ids, out, num_label);
}

// Round 2
// 737.024 us; speedup vs baseline: 1.1775x; 1.1775x over previous
//
#include <hip/hip_runtime.h>

typedef __attribute__((ext_vector_type(8))) short short8;
typedef __attribute__((ext_vector_type(8))) unsigned short ushort8;
typedef __attribute__((ext_vector_type(4))) unsigned short ushort4_t;
typedef __attribute__((ext_vector_type(4))) float floatx4;

#define NUM_AUTHORS 200000
#define HID 128
#define ABITS 9   // 512 authors per bucket
#define NB 391    // ceil(200000 / 512)
#define CHUNK 8192
#define TPB 32    // tiles (16 rows each) per block in gemm_mfma
#define OSTRIDE 136  // Obuf row stride in ushorts (272 B: 64+4 dwords, breaks bank alias)

__device__ __forceinline__ unsigned short f32_to_bf16(float f) {
  union { float f; unsigned int u; } v; v.f = f;
  unsigned int u = v.u;
  u += 0x7FFF + ((u >> 16) & 1);   // round-to-nearest-even
  return (unsigned short)(u >> 16);
}
__device__ __forceinline__ float bf16_to_f32(unsigned short h) {
  union { unsigned int u; float f; } v; v.u = ((unsigned int)h) << 16; return v.f;
}

// W[128][128] fp32 -> fragment-ordered bf16 image for MFMA "A" operand.
// Fragment f = tt*4+ks; unit idx = f*64 + lane; lane holds outcol = tt*16+(lane&15),
// k = ks*32+(lane>>4)*8 + j.  Wfrag[idx*8 + j] = bf16(W[k][outcol]).
__global__ __launch_bounds__(256) void prep_w(
    const float* __restrict__ Wp, const float* __restrict__ Wa,
    unsigned short* __restrict__ WtP, unsigned short* __restrict__ WtA)
{
  const float* W = blockIdx.x ? Wa : Wp;
  unsigned short* Wt = blockIdx.x ? WtA : WtP;
  int t = threadIdx.x;
#pragma unroll
  for (int i = 0; i < 8; ++i) {
    int idx = i * 256 + t;          // 0..2047
    int f = idx >> 6;
    int lane = idx & 63;
    int tt = f >> 2, ks = f & 3;
    int m = lane & 15, q = lane >> 4;
    int col = tt * 16 + m;
    int kb = ks * 32 + q * 8;
    ushort8 h;
#pragma unroll
    for (int j = 0; j < 8; ++j) h[j] = f32_to_bf16(W[(size_t)(kb + j) * HID + col]);
    *(ushort8*)&Wt[(size_t)idx * 8] = h;
  }
}

// Y[M,128](bf16) = rowscale(X[M,128]) @ W[128,128] + bias
// Barrier-free reg-resident MFMA; block-contiguous tile ranges (L3-friendly sweep);
// output transposed through per-wave LDS buffer -> full-64B-line stores.
template<bool X_IS_BF16>
__global__ __launch_bounds__(256, 4) void gemm_mfma(
    const void* __restrict__ Xv, const unsigned short* __restrict__ Wfrag,
    const float* __restrict__ bias, const int* __restrict__ counts,
    unsigned short* __restrict__ Y, int M, int nTiles)
{
  __shared__ unsigned short Bs[32 * 64 * 8];        // 32 KB W fragments
  __shared__ unsigned short Obuf[4 * 16 * OSTRIDE]; // 4 waves x 16 rows x 272B
  const int t = threadIdx.x;
#pragma unroll
  for (int i = 0; i < 8; ++i) {
    int g = i * 256 + t;
    *(ushort8*)&Bs[(size_t)g * 8] = *(const ushort8*)&Wfrag[(size_t)g * 8];
  }
  __syncthreads();

  const int w = t >> 6;
  const int lane = t & 63;
  const int m = lane & 15;
  const int q = lane >> 4;
  unsigned short* ob = &Obuf[w * 16 * OSTRIDE];

  const int tileBase = blockIdx.x * TPB;

#pragma unroll 1
  for (int i = 0; i < TPB / 4; ++i) {
    const int tile = tileBase + i * 4 + w;
    if (tile >= nTiles) break;
    const int p = tile * 16 + m;           // this lane's input row
    const bool valid = (p < M);

    // X fragments: lane holds X[p][ks*32 + q*8 .. +8] for ks=0..3
    short8 xf[4];
    if (X_IS_BF16) {
      const unsigned short* X = (const unsigned short*)Xv;
      const unsigned short* xp = X + (size_t)p * HID + q * 8;
#pragma unroll
      for (int ks = 0; ks < 4; ++ks) {
        if (valid) xf[ks] = *(const short8*)(xp + ks * 32);
        else       xf[ks] = (short8)0;
      }
    } else {
      const float* X = (const float*)Xv;
      const float* xp = X + (size_t)p * HID + q * 8;
#pragma unroll
      for (int ks = 0; ks < 4; ++ks) {
        float4 a0, a1;
        if (valid) {
          a0 = *(const float4*)(xp + ks * 32);
          a1 = *(const float4*)(xp + ks * 32 + 4);
        } else {
          a0 = make_float4(0.f, 0.f, 0.f, 0.f); a1 = a0;
        }
        short8 h;
        h[0] = (short)f32_to_bf16(a0.x); h[1] = (short)f32_to_bf16(a0.y);
        h[2] = (short)f32_to_bf16(a0.z); h[3] = (short)f32_to_bf16(a0.w);
        h[4] = (short)f32_to_bf16(a1.x); h[5] = (short)f32_to_bf16(a1.y);
        h[6] = (short)f32_to_bf16(a1.z); h[7] = (short)f32_to_bf16(a1.w);
        xf[ks] = h;
      }
    }

    floatx4 acc[8];
#pragma unroll
    for (int tt = 0; tt < 8; ++tt) acc[tt] = (floatx4)(0.f);

#pragma unroll
    for (int ks = 0; ks < 4; ++ks) {
#pragma unroll
      for (int tt = 0; tt < 8; ++tt) {
        short8 wf = *(const short8*)&Bs[(size_t)((tt * 4 + ks) * 64 + lane) * 8];
        acc[tt] = __builtin_amdgcn_mfma_f32_16x16x32_bf16(wf, xf[ks], acc[tt], 0, 0, 0);
      }
    }

    float inv = 1.0f;
    if (counts) {
      float c = valid ? (float)counts[p] : 1.0f;
      inv = 1.0f / fmaxf(c, 1.0f);
    }

    // epilogue -> per-wave LDS tile (lane holds 4 consecutive cols per tt)
#pragma unroll
    for (int tt = 0; tt < 8; ++tt) {
      const float4 bv = *(const float4*)(bias + tt * 16 + q * 4);
      ushort4_t o;
      o[0] = f32_to_bf16(acc[tt][0] * inv + bv.x);
      o[1] = f32_to_bf16(acc[tt][1] * inv + bv.y);
      o[2] = f32_to_bf16(acc[tt][2] * inv + bv.z);
      o[3] = f32_to_bf16(acc[tt][3] * inv + bv.w);
      *(ushort4_t*)&ob[m * OSTRIDE + tt * 16 + q * 4] = o;
    }
    asm volatile("s_waitcnt lgkmcnt(0)" ::: "memory");

    // coalesced store: lane reads row (lane&15), 16B chunk (lane>>4); 4 insts
    // cover 16 rows x 256B; each inst writes a full 64B line per row.
    {
      const int r = lane & 15;
      const int c = lane >> 4;
      const int row = tile * 16 + r;
#pragma unroll
      for (int j = 0; j < 4; ++j) {
        ushort8 v = *(const ushort8*)&ob[r * OSTRIDE + j * 32 + c * 8];
        if (row < M)
          *(ushort8*)(Y + (size_t)row * HID + j * 32 + c * 8) = v;
      }
    }
    asm volatile("s_waitcnt lgkmcnt(0)" ::: "memory");  // Obuf reads done before next iter overwrites
  }
}

// ---- author-count histogram + scan (for offsets/cnt) ----
__global__ __launch_bounds__(256) void hist_kernel(
    const int* __restrict__ aid, int* __restrict__ cnt, int n)
{
  int i = blockIdx.x * 256 + threadIdx.x;
  if (i < n) atomicAdd(&cnt[aid[i]], 1);
}

__global__ __launch_bounds__(256) void scan1(
    const int* __restrict__ cnt, int* __restrict__ offsets,
    int* __restrict__ blockSums, int n)
{
  __shared__ int s[256];
  int t = threadIdx.x;
  int i = blockIdx.x * 256 + t;
  int v = (i < n) ? cnt[i] : 0;
  s[t] = v; __syncthreads();
#pragma unroll
  for (int off = 1; off < 256; off <<= 1) {
    int tv = 0;
    if (t >= off) tv = s[t - off];
    __syncthreads();
    if (t >= off) s[t] += tv;
    __syncthreads();
  }
  if (i < n) offsets[i] = s[t] - v;
  if (t == 255) blockSums[blockIdx.x] = s[255];
}

__global__ __launch_bounds__(1024) void scan2(int* __restrict__ blockSums, int nb)
{
  __shared__ int s[1024];
  int t = threadIdx.x;
  int v = (t < nb) ? blockSums[t] : 0;
  s[t] = v; __syncthreads();
#pragma unroll
  for (int off = 1; off < 1024; off <<= 1) {
    int tv = 0;
    if (t >= off) tv = s[t - off];
    __syncthreads();
    if (t >= off) s[t] += tv;
    __syncthreads();
  }
  if (t < nb) blockSums[t] = s[t] - v;
}

__global__ __launch_bounds__(256) void scan3(
    int* __restrict__ offsets, const int* __restrict__ blockSums, int n)
{
  int i = blockIdx.x * 256 + threadIdx.x;
  if (i < n) offsets[i] += blockSums[blockIdx.x];
}

// ---- two-level radix partition ----
__global__ __launch_bounds__(256) void bucket_hist(
    const int* __restrict__ aid, int* __restrict__ bcnt, int n)
{
  __shared__ int hist[NB];
  int t = threadIdx.x;
  for (int i = t; i < NB; i += 256) hist[i] = 0;
  __syncthreads();
  int e0 = blockIdx.x * CHUNK;
  int e1 = min(e0 + CHUNK, n);
  for (int e = e0 + t; e < e1; e += 256) atomicAdd(&hist[aid[e] >> ABITS], 1);
  __syncthreads();
  for (int i = t; i < NB; i += 256) {
    int h = hist[i];
    if (h) atomicAdd(&bcnt[i], h);
  }
}

__global__ __launch_bounds__(512) void bucket_scan(
    const int* __restrict__ bcnt, int* __restrict__ boff, int* __restrict__ bcur, int n)
{
  __shared__ int s[512];
  int t = threadIdx.x;
  int v = (t < NB) ? bcnt[t] : 0;
  s[t] = v; __syncthreads();
#pragma unroll
  for (int off = 1; off < 512; off <<= 1) {
    int tv = 0;
    if (t >= off) tv = s[t - off];
    __syncthreads();
    if (t >= off) s[t] += tv;
    __syncthreads();
  }
  if (t < NB) { int e = s[t] - v; boff[t] = e; bcur[t] = e; }
  if (t == 0) boff[NB] = n;
}

__global__ __launch_bounds__(256) void partA(
    const int* __restrict__ aid, const int* __restrict__ pid,
    int* __restrict__ bcur, uint2* __restrict__ pairs, int n)
{
  __shared__ int hist[NB];
  __shared__ int cur[NB];
  int t = threadIdx.x;
  for (int i = t; i < NB; i += 256) hist[i] = 0;
  __syncthreads();
  int e0 = blockIdx.x * CHUNK;
  int e1 = min(e0 + CHUNK, n);
  for (int e = e0 + t; e < e1; e += 256) atomicAdd(&hist[aid[e] >> ABITS], 1);
  __syncthreads();
  for (int i = t; i < NB; i += 256) {
    int h = hist[i];
    cur[i] = h ? atomicAdd(&bcur[i], h) : 0;
  }
  __syncthreads();
  for (int e = e0 + t; e < e1; e += 256) {
    int a = aid[e];
    int pos = atomicAdd(&cur[a >> ABITS], 1);
    pairs[pos] = make_uint2((unsigned)a, (unsigned)pid[e]);
  }
}

__global__ __launch_bounds__(256) void partB(
    const uint2* __restrict__ pairs, const int* __restrict__ boff,
    const int* __restrict__ offsets, int* __restrict__ csr)
{
  __shared__ int lcur[1 << ABITS];
  int b = blockIdx.x;
  int t = threadIdx.x;
  int a0 = b << ABITS;
  for (int i = t; i < (1 << ABITS); i += 256) {
    int g = a0 + i;
    lcur[i] = (g < NUM_AUTHORS) ? offsets[g] : 0;
  }
  __syncthreads();
  int s = boff[b], e = boff[b + 1];
  for (int i = s + t; i < e; i += 256) {
    uint2 pr = pairs[i];
    int pos = atomicAdd(&lcur[pr.x - a0], 1);
    csr[pos] = (int)pr.y;
  }
}

// One wave per author; 4x16-lane groups each gather one 256B row per iter.
__global__ __launch_bounds__(256) void accumulate_kernel(
    const unsigned short* __restrict__ paper_hb, const int* __restrict__ csr,
    const int* __restrict__ offsets, const int* __restrict__ cnt,
    unsigned short* __restrict__ author_in)
{
  int a = blockIdx.x * 4 + (threadIdx.x >> 6);
  if (a >= NUM_AUTHORS) return;
  int lane = threadIdx.x & 63;
  int sub = lane >> 4;
  int c16 = lane & 15;
  int start = offsets[a];
  int n = cnt[a];
  float acc[8];
#pragma unroll
  for (int j = 0; j < 8; ++j) acc[j] = 0.f;
  for (int i = 0; i < n; i += 4) {
    int idx = i + sub;
    if (idx < n) {
      int p = csr[start + idx];
      ushort8 h = *(const ushort8*)(paper_hb + (size_t)p * HID + c16 * 8);
#pragma unroll
      for (int j = 0; j < 8; ++j) acc[j] += bf16_to_f32(h[j]);
    }
  }
#pragma unroll
  for (int j = 0; j < 8; ++j) {
    acc[j] += __shfl_xor(acc[j], 16, 64);
    acc[j] += __shfl_xor(acc[j], 32, 64);
  }
  if (sub == 0) {
    ushort8 o;
#pragma unroll
    for (int j = 0; j < 8; ++j) o[j] = f32_to_bf16(acc[j]);
    *(ushort8*)(author_in + (size_t)a * HID + c16 * 8) = o;
  }
}

// One edge per 16-lane group; 16B loads/lane.
__global__ __launch_bounds__(256) void dot_kernel(
    const unsigned short* __restrict__ author_hb, const unsigned short* __restrict__ paper_hb,
    const int* __restrict__ la, const int* __restrict__ lp,
    float* __restrict__ out, int n)
{
  int e = blockIdx.x * 16 + (threadIdx.x >> 4);
  if (e >= n) return;
  int c16 = threadIdx.x & 15;
  int a = la[e], p = lp[e];
  ushort8 ah = *(const ushort8*)(author_hb + (size_t)a * HID + c16 * 8);
  ushort8 ph = *(const ushort8*)(paper_hb + (size_t)p * HID + c16 * 8);
  float s = 0.f;
#pragma unroll
  for (int j = 0; j < 8; ++j) s += bf16_to_f32(ah[j]) * bf16_to_f32(ph[j]);
  s += __shfl_xor(s, 1, 64);
  s += __shfl_xor(s, 2, 64);
  s += __shfl_xor(s, 4, 64);
  s += __shfl_xor(s, 8, 64);
  if (c16 == 0) out[e] = s;
}

extern "C" void kernel_launch(void* const* d_in, const int* in_sizes, int n_in,
                              void* d_out, int out_size, void* d_ws, size_t ws_size,
                              hipStream_t stream)
{
  const float* paper_x          = (const float*)d_in[0];
  const int*   author_ids       = (const int*)d_in[1];
  const int*   paper_ids        = (const int*)d_in[2];
  const int*   label_author_ids = (const int*)d_in[3];
  const int*   label_paper_ids  = (const int*)d_in[4];
  const float* W_paper          = (const float*)d_in[5];
  const float* b_paper          = (const float*)d_in[6];
  const float* W_author         = (const float*)d_in[7];
  const float* b_author         = (const float*)d_in[8];
  float* out = (float*)d_out;

  const int num_papers = in_sizes[0] / HID;
  const int num_edges  = in_sizes[1];
  const int num_label  = in_sizes[3];
  const int NA = NUM_AUTHORS;

  char* ws = (char*)d_ws;
  size_t off = 0;
  auto alloc = [&](size_t bytes) { void* p = ws + off; off = (off + bytes + 255) & ~(size_t)255; return p; };
  unsigned short* paper_hb  = (unsigned short*)alloc((size_t)num_papers * HID * 2);
  unsigned short* author_in = (unsigned short*)alloc((size_t)NA * HID * 2);
  unsigned short* author_hb = (unsigned short*)alloc((size_t)NA * HID * 2);
  int* counts_int = (int*)alloc((size_t)NA * 4);
  int* bcnt       = (int*)alloc((size_t)(NB + 1) * 4);
  int* boff       = (int*)alloc((size_t)(NB + 1) * 4);
  int* bcur       = (int*)alloc((size_t)NB * 4);
  int* offsets    = (int*)alloc((size_t)NA * 4);
  int* blockSums  = (int*)alloc(1024 * 4);
  int* csr        = (int*)alloc((size_t)num_edges * 4);
  uint2* pairs    = (uint2*)alloc((size_t)num_edges * 8);
  unsigned short* WtP = (unsigned short*)alloc(HID * HID * 2);
  unsigned short* WtA = (unsigned short*)alloc(HID * HID * 2);

  hipMemsetAsync(counts_int, 0, (size_t)NA * 4, stream);
  hipMemsetAsync(bcnt, 0, (size_t)(NB + 1) * 4, stream);

  prep_w<<<2, 256, 0, stream>>>(W_paper, W_author, WtP, WtA);

  // paper GEMM: contiguous 32-tile (512-row) ranges per block
  {
    const int nTiles = (num_papers + 15) / 16;
    const int blocks = (nTiles + TPB - 1) / TPB;
    gemm_mfma<false><<<blocks, 256, 0, stream>>>(
        paper_x, WtP, b_paper, nullptr, paper_hb, num_papers, nTiles);
  }

  hist_kernel<<<(num_edges + 255) / 256, 256, 0, stream>>>(author_ids, counts_int, num_edges);

  const int nb = (NA + 255) / 256;   // 782 <= 1024
  scan1<<<nb, 256, 0, stream>>>(counts_int, offsets, blockSums, NA);
  scan2<<<1, 1024, 0, stream>>>(blockSums, nb);
  scan3<<<nb, 256, 0, stream>>>(offsets, blockSums, NA);

  const int nchunks = (num_edges + CHUNK - 1) / CHUNK;
  bucket_hist<<<nchunks, 256, 0, stream>>>(author_ids, bcnt, num_edges);
  bucket_scan<<<1, 512, 0, stream>>>(bcnt, boff, bcur, num_edges);
  partA<<<nchunks, 256, 0, stream>>>(author_ids, paper_ids, bcur, pairs, num_edges);
  partB<<<NB, 256, 0, stream>>>(pairs, boff, offsets, csr);

  accumulate_kernel<<<(NA + 3) / 4, 256, 0, stream>>>(
      paper_hb, csr, offsets, counts_int, author_in);

  // author GEMM
  {
    const int nTiles = (NA + 15) / 16;
    const int blocks = (nTiles + TPB - 1) / TPB;
    gemm_mfma<true><<<blocks, 256, 0, stream>>>(
        author_in, WtA, b_author, counts_int, author_hb, NA, nTiles);
  }

  dot_kernel<<<(num_label + 15) / 16, 256, 0, stream>>>(
      author_hb, paper_hb, label_author_ids, label_paper_ids, out, num_label);
}

// Round 4
// 670.029 us; speedup vs baseline: 1.2952x; 1.1000x over previous
//
#include <hip/hip_runtime.h>

typedef __attribute__((ext_vector_type(8))) short short8;
typedef __attribute__((ext_vector_type(8))) unsigned short ushort8;
typedef __attribute__((ext_vector_type(4))) unsigned short ushort4_t;
typedef __attribute__((ext_vector_type(4))) float floatx4;

#define NUM_AUTHORS 200000
#define HID 128
#define ABITS 9   // 512 authors per bucket
#define NB 391    // ceil(200000 / 512)
#define CHUNK 8192
#define OSTRIDE 136  // Obuf row stride in ushorts (272 B)

__device__ __forceinline__ unsigned short f32_to_bf16(float f) {
  union { float f; unsigned int u; } v; v.f = f;
  unsigned int u = v.u;
  u += 0x7FFF + ((u >> 16) & 1);   // round-to-nearest-even
  return (unsigned short)(u >> 16);
}
__device__ __forceinline__ float bf16_to_f32(unsigned short h) {
  union { unsigned int u; float f; } v; v.u = ((unsigned int)h) << 16; return v.f;
}

// W[128][128] fp32 -> fragment-ordered bf16 image for MFMA "A" operand.
__global__ __launch_bounds__(256) void prep_w(
    const float* __restrict__ Wp, const float* __restrict__ Wa,
    unsigned short* __restrict__ WtP, unsigned short* __restrict__ WtA)
{
  const float* W = blockIdx.x ? Wa : Wp;
  unsigned short* Wt = blockIdx.x ? WtA : WtP;
  int t = threadIdx.x;
#pragma unroll
  for (int i = 0; i < 8; ++i) {
    int idx = i * 256 + t;          // 0..2047
    int f = idx >> 6;
    int lane = idx & 63;
    int tt = f >> 2, ks = f & 3;
    int m = lane & 15, q = lane >> 4;
    int col = tt * 16 + m;
    int kb = ks * 32 + q * 8;
    ushort8 h;
#pragma unroll
    for (int j = 0; j < 8; ++j) h[j] = f32_to_bf16(W[(size_t)(kb + j) * HID + col]);
    *(ushort8*)&Wt[(size_t)idx * 8] = h;
  }
}

// Y[M,128](bf16) = rowscale(X[M,128]) @ W[128,128] + bias
// Barrier-free reg-resident MFMA; exact-fit persistent grid with contiguous
// tile ranges; output transposed through per-wave LDS -> full-64B-line stores.
template<bool X_IS_BF16>
__global__ __launch_bounds__(256, 4) void gemm_mfma(
    const void* __restrict__ Xv, const unsigned short* __restrict__ Wfrag,
    const float* __restrict__ bias, const int* __restrict__ counts,
    unsigned short* __restrict__ Y, int M, int nTiles, int tpb)
{
  __shared__ unsigned short Bs[32 * 64 * 8];        // 32 KB W fragments
  __shared__ unsigned short Obuf[4 * 16 * OSTRIDE]; // 4 waves x 16 rows x 272B
  const int t = threadIdx.x;
#pragma unroll
  for (int i = 0; i < 8; ++i) {
    int g = i * 256 + t;
    *(ushort8*)&Bs[(size_t)g * 8] = *(const ushort8*)&Wfrag[(size_t)g * 8];
  }
  __syncthreads();

  const int w = t >> 6;
  const int lane = t & 63;
  const int m = lane & 15;
  const int q = lane >> 4;
  unsigned short* ob = &Obuf[w * 16 * OSTRIDE];

  const int t0 = blockIdx.x * tpb;
  const int t1 = min(t0 + tpb, nTiles);

#pragma unroll 1
  for (int tile = t0 + w; tile < t1; tile += 4) {
    const int p = tile * 16 + m;           // this lane's input row
    const bool valid = (p < M);

    // X fragments: lane holds X[p][ks*32 + q*8 .. +8] for ks=0..3
    short8 xf[4];
    if (X_IS_BF16) {
      const unsigned short* X = (const unsigned short*)Xv;
      const unsigned short* xp = X + (size_t)p * HID + q * 8;
#pragma unroll
      for (int ks = 0; ks < 4; ++ks) {
        if (valid) xf[ks] = *(const short8*)(xp + ks * 32);
        else       xf[ks] = (short8)0;
      }
    } else {
      const float* X = (const float*)Xv;
      const float* xp = X + (size_t)p * HID + q * 8;
#pragma unroll
      for (int ks = 0; ks < 4; ++ks) {
        floatx4 a0, a1;
        if (valid) {
          a0 = __builtin_nontemporal_load((const floatx4*)(xp + ks * 32));
          a1 = __builtin_nontemporal_load((const floatx4*)(xp + ks * 32 + 4));
        } else {
          a0 = (floatx4)(0.f); a1 = (floatx4)(0.f);
        }
        short8 h;
        h[0] = (short)f32_to_bf16(a0[0]); h[1] = (short)f32_to_bf16(a0[1]);
        h[2] = (short)f32_to_bf16(a0[2]); h[3] = (short)f32_to_bf16(a0[3]);
        h[4] = (short)f32_to_bf16(a1[0]); h[5] = (short)f32_to_bf16(a1[1]);
        h[6] = (short)f32_to_bf16(a1[2]); h[7] = (short)f32_to_bf16(a1[3]);
        xf[ks] = h;
      }
    }

    floatx4 acc[8];
#pragma unroll
    for (int tt = 0; tt < 8; ++tt) acc[tt] = (floatx4)(0.f);

#pragma unroll
    for (int ks = 0; ks < 4; ++ks) {
#pragma unroll
      for (int tt = 0; tt < 8; ++tt) {
        short8 wf = *(const short8*)&Bs[(size_t)((tt * 4 + ks) * 64 + lane) * 8];
        acc[tt] = __builtin_amdgcn_mfma_f32_16x16x32_bf16(wf, xf[ks], acc[tt], 0, 0, 0);
      }
    }

    float inv = 1.0f;
    if (counts) {
      float c = valid ? (float)counts[p] : 1.0f;
      inv = 1.0f / fmaxf(c, 1.0f);
    }

    // epilogue -> per-wave LDS tile (lane holds 4 consecutive cols per tt)
#pragma unroll
    for (int tt = 0; tt < 8; ++tt) {
      const float4 bv = *(const float4*)(bias + tt * 16 + q * 4);
      ushort4_t o;
      o[0] = f32_to_bf16(acc[tt][0] * inv + bv.x);
      o[1] = f32_to_bf16(acc[tt][1] * inv + bv.y);
      o[2] = f32_to_bf16(acc[tt][2] * inv + bv.z);
      o[3] = f32_to_bf16(acc[tt][3] * inv + bv.w);
      *(ushort4_t*)&ob[m * OSTRIDE + tt * 16 + q * 4] = o;
    }
    asm volatile("s_waitcnt lgkmcnt(0)" ::: "memory");

    // coalesced store: lane reads row (lane&15), 16B chunk (lane>>4)
    {
      const int r = lane & 15;
      const int c = lane >> 4;
      const int row = tile * 16 + r;
#pragma unroll
      for (int j = 0; j < 4; ++j) {
        ushort8 v = *(const ushort8*)&ob[r * OSTRIDE + j * 32 + c * 8];
        if (row < M)
          *(ushort8*)(Y + (size_t)row * HID + j * 32 + c * 8) = v;
      }
    }
    asm volatile("s_waitcnt lgkmcnt(0)" ::: "memory");  // Obuf reads done before next iter
  }
}

// ---- author-count histogram + scan ----
__global__ __launch_bounds__(256) void hist_kernel(
    const int* __restrict__ aid, int* __restrict__ cnt, int n)
{
  int i = blockIdx.x * 256 + threadIdx.x;
  if (i < n) atomicAdd(&cnt[aid[i]], 1);
}

__global__ __launch_bounds__(256) void scan1(
    const int* __restrict__ cnt, int* __restrict__ offsets,
    int* __restrict__ blockSums, int n)
{
  __shared__ int s[256];
  int t = threadIdx.x;
  int i = blockIdx.x * 256 + t;
  int v = (i < n) ? cnt[i] : 0;
  s[t] = v; __syncthreads();
#pragma unroll
  for (int off = 1; off < 256; off <<= 1) {
    int tv = 0;
    if (t >= off) tv = s[t - off];
    __syncthreads();
    if (t >= off) s[t] += tv;
    __syncthreads();
  }
  if (i < n) offsets[i] = s[t] - v;
  if (t == 255) blockSums[blockIdx.x] = s[255];
}

// Fused: add block prefix (computed redundantly per block), finalize offsets,
// and derive bucket table boff/bcur from offsets (bucket = author >> ABITS,
// so bucket boundaries align with author boundaries in CSR order).
__global__ __launch_bounds__(256) void scan3b(
    int* __restrict__ offsets, const int* __restrict__ blockSums,
    const int* __restrict__ cnt, int* __restrict__ boff, int* __restrict__ bcur,
    int n)
{
  __shared__ int s[256];
  const int t = threadIdx.x;
  const int bid = blockIdx.x;
  int part = 0;
  for (int j = t; j < bid; j += 256) part += blockSums[j];
  s[t] = part; __syncthreads();
#pragma unroll
  for (int off = 128; off > 0; off >>= 1) {
    if (t < off) s[t] += s[t + off];
    __syncthreads();
  }
  const int prefix = s[0];
  const int i = bid * 256 + t;
  if (i < n) {
    int fin = offsets[i] + prefix;
    offsets[i] = fin;
    if ((i & 511) == 0) { int b = i >> ABITS; boff[b] = fin; bcur[b] = fin; }
    if (i == n - 1) boff[NB] = fin + cnt[i];
  }
}

// partition (aid,pid) pairs bucket-major; LDS-binned
__global__ __launch_bounds__(256) void partA(
    const int* __restrict__ aid, const int* __restrict__ pid,
    int* __restrict__ bcur, uint2* __restrict__ pairs, int n)
{
  __shared__ int hist[NB];
  __shared__ int cur[NB];
  int t = threadIdx.x;
  for (int i = t; i < NB; i += 256) hist[i] = 0;
  __syncthreads();
  int e0 = blockIdx.x * CHUNK;
  int e1 = min(e0 + CHUNK, n);
  for (int e = e0 + t; e < e1; e += 256) atomicAdd(&hist[aid[e] >> ABITS], 1);
  __syncthreads();
  for (int i = t; i < NB; i += 256) {
    int h = hist[i];
    cur[i] = h ? atomicAdd(&bcur[i], h) : 0;
  }
  __syncthreads();
  for (int e = e0 + t; e < e1; e += 256) {
    int a = aid[e];
    int pos = atomicAdd(&cur[a >> ABITS], 1);
    pairs[pos] = make_uint2((unsigned)a, (unsigned)pid[e]);
  }
}

// one block per bucket: scatter pids into this bucket's csr window
__global__ __launch_bounds__(256) void partB(
    const uint2* __restrict__ pairs, const int* __restrict__ boff,
    const int* __restrict__ offsets, int* __restrict__ csr)
{
  __shared__ int lcur[1 << ABITS];
  int b = blockIdx.x;
  int t = threadIdx.x;
  int a0 = b << ABITS;
  for (int i = t; i < (1 << ABITS); i += 256) {
    int g = a0 + i;
    lcur[i] = (g < NUM_AUTHORS) ? offsets[g] : 0;
  }
  __syncthreads();
  int s = boff[b], e = boff[b + 1];
  for (int i = s + t; i < e; i += 256) {
    uint2 pr = pairs[i];
    int pos = atomicAdd(&lcur[pr.x - a0], 1);
    csr[pos] = (int)pr.y;
  }
}

// One wave per author; 4x16-lane groups, 2 gathers in flight per group.
__global__ __launch_bounds__(256) void accumulate_kernel(
    const unsigned short* __restrict__ paper_hb, const int* __restrict__ csr,
    const int* __restrict__ offsets, const int* __restrict__ cnt,
    unsigned short* __restrict__ author_in)
{
  int a = blockIdx.x * 4 + (threadIdx.x >> 6);
  if (a >= NUM_AUTHORS) return;
  int lane = threadIdx.x & 63;
  int sub = lane >> 4;
  int c16 = lane & 15;
  int start = offsets[a];
  int n = cnt[a];
  float acc[8];
#pragma unroll
  for (int j = 0; j < 8; ++j) acc[j] = 0.f;
  for (int i = 0; i < n; i += 8) {
    int idx0 = i + sub;
    int idx1 = i + 4 + sub;
    bool v0 = idx0 < n, v1 = idx1 < n;
    int p0 = v0 ? csr[start + idx0] : 0;
    int p1 = v1 ? csr[start + idx1] : 0;
    ushort8 h0, h1;
    if (v0) h0 = *(const ushort8*)(paper_hb + (size_t)p0 * HID + c16 * 8);
    if (v1) h1 = *(const ushort8*)(paper_hb + (size_t)p1 * HID + c16 * 8);
    if (v0) {
#pragma unroll
      for (int j = 0; j < 8; ++j) acc[j] += bf16_to_f32(h0[j]);
    }
    if (v1) {
#pragma unroll
      for (int j = 0; j < 8; ++j) acc[j] += bf16_to_f32(h1[j]);
    }
  }
#pragma unroll
  for (int j = 0; j < 8; ++j) {
    acc[j] += __shfl_xor(acc[j], 16, 64);
    acc[j] += __shfl_xor(acc[j], 32, 64);
  }
  if (sub == 0) {
    ushort8 o;
#pragma unroll
    for (int j = 0; j < 8; ++j) o[j] = f32_to_bf16(acc[j]);
    *(ushort8*)(author_in + (size_t)a * HID + c16 * 8) = o;
  }
}

// One edge per 16-lane group; 16B loads/lane.
__global__ __launch_bounds__(256) void dot_kernel(
    const unsigned short* __restrict__ author_hb, const unsigned short* __restrict__ paper_hb,
    const int* __restrict__ la, const int* __restrict__ lp,
    float* __restrict__ out, int n)
{
  int e = blockIdx.x * 16 + (threadIdx.x >> 4);
  if (e >= n) return;
  int c16 = threadIdx.x & 15;
  int a = la[e], p = lp[e];
  ushort8 ah = *(const ushort8*)(author_hb + (size_t)a * HID + c16 * 8);
  ushort8 ph = *(const ushort8*)(paper_hb + (size_t)p * HID + c16 * 8);
  float s = 0.f;
#pragma unroll
  for (int j = 0; j < 8; ++j) s += bf16_to_f32(ah[j]) * bf16_to_f32(ph[j]);
  s += __shfl_xor(s, 1, 64);
  s += __shfl_xor(s, 2, 64);
  s += __shfl_xor(s, 4, 64);
  s += __shfl_xor(s, 8, 64);
  if (c16 == 0) __builtin_nontemporal_store(s, &out[e]);
}

extern "C" void kernel_launch(void* const* d_in, const int* in_sizes, int n_in,
                              void* d_out, int out_size, void* d_ws, size_t ws_size,
                              hipStream_t stream)
{
  const float* paper_x          = (const float*)d_in[0];
  const int*   author_ids       = (const int*)d_in[1];
  const int*   paper_ids        = (const int*)d_in[2];
  const int*   label_author_ids = (const int*)d_in[3];
  const int*   label_paper_ids  = (const int*)d_in[4];
  const float* W_paper          = (const float*)d_in[5];
  const float* b_paper          = (const float*)d_in[6];
  const float* W_author         = (const float*)d_in[7];
  const float* b_author         = (const float*)d_in[8];
  float* out = (float*)d_out;

  const int num_papers = in_sizes[0] / HID;
  const int num_edges  = in_sizes[1];
  const int num_label  = in_sizes[3];
  const int NA = NUM_AUTHORS;

  char* ws = (char*)d_ws;
  size_t off = 0;
  auto alloc = [&](size_t bytes) { void* p = ws + off; off = (off + bytes + 255) & ~(size_t)255; return p; };
  unsigned short* paper_hb  = (unsigned short*)alloc((size_t)num_papers * HID * 2);
  unsigned short* author_in = (unsigned short*)alloc((size_t)NA * HID * 2);
  unsigned short* author_hb = (unsigned short*)alloc((size_t)NA * HID * 2);
  int* counts_int = (int*)alloc((size_t)NA * 4);
  int* boff       = (int*)alloc((size_t)(NB + 1) * 4);
  int* bcur       = (int*)alloc((size_t)NB * 4);
  int* offsets    = (int*)alloc((size_t)NA * 4);
  int* blockSums  = (int*)alloc(1024 * 4);
  int* csr        = (int*)alloc((size_t)num_edges * 4);
  uint2* pairs    = (uint2*)alloc((size_t)num_edges * 8);
  unsigned short* WtP = (unsigned short*)alloc(HID * HID * 2);
  unsigned short* WtA = (unsigned short*)alloc(HID * HID * 2);

  hipMemsetAsync(counts_int, 0, (size_t)NA * 4, stream);

  prep_w<<<2, 256, 0, stream>>>(W_paper, W_author, WtP, WtA);

  // paper GEMM: exact-fit persistent grid (<=768 blocks = 3/CU), contiguous ranges
  {
    const int nTiles = (num_papers + 15) / 16;
    int tpb = (nTiles + 767) / 768;
    int blocks = (nTiles + tpb - 1) / tpb;
    gemm_mfma<false><<<blocks, 256, 0, stream>>>(
        paper_x, WtP, b_paper, nullptr, paper_hb, num_papers, nTiles, tpb);
  }

  hist_kernel<<<(num_edges + 255) / 256, 256, 0, stream>>>(author_ids, counts_int, num_edges);

  const int nb = (NA + 255) / 256;   // 782
  scan1<<<nb, 256, 0, stream>>>(counts_int, offsets, blockSums, NA);
  scan3b<<<nb, 256, 0, stream>>>(offsets, blockSums, counts_int, boff, bcur, NA);

  const int nchunks = (num_edges + CHUNK - 1) / CHUNK;
  partA<<<nchunks, 256, 0, stream>>>(author_ids, paper_ids, bcur, pairs, num_edges);
  partB<<<NB, 256, 0, stream>>>(pairs, boff, offsets, csr);

  accumulate_kernel<<<(NA + 3) / 4, 256, 0, stream>>>(
      paper_hb, csr, offsets, counts_int, author_in);

  // author GEMM
  {
    const int nTiles = (NA + 15) / 16;
    int tpb = (nTiles + 767) / 768;
    int blocks = (nTiles + tpb - 1) / tpb;
    gemm_mfma<true><<<blocks, 256, 0, stream>>>(
        author_in, WtA, b_author, counts_int, author_hb, NA, nTiles, tpb);
  }

  dot_kernel<<<(num_label + 15) / 16, 256, 0, stream>>>(
      author_hb, paper_hb, label_author_ids, label_paper_ids, out, num_label);
}

// Round 5
// 592.403 us; speedup vs baseline: 1.4650x; 1.1310x over previous
//
#include <hip/hip_runtime.h>

typedef __attribute__((ext_vector_type(8))) short short8;
typedef __attribute__((ext_vector_type(8))) unsigned short ushort8;
typedef __attribute__((ext_vector_type(4))) unsigned short ushort4_t;
typedef __attribute__((ext_vector_type(4))) float floatx4;

#define NUM_AUTHORS 200000
#define HID 128
#define ABITS 9   // 512 authors per bucket
#define NB 391    // ceil(200000 / 512)
#define CHUNK 8192
#define OSTRIDE 136  // Obuf row stride in ushorts (272 B)

__device__ __forceinline__ unsigned short f32_to_bf16(float f) {
  union { float f; unsigned int u; } v; v.f = f;
  unsigned int u = v.u;
  u += 0x7FFF + ((u >> 16) & 1);   // round-to-nearest-even
  return (unsigned short)(u >> 16);
}
__device__ __forceinline__ float bf16_to_f32(unsigned short h) {
  union { unsigned int u; float f; } v; v.u = ((unsigned int)h) << 16; return v.f;
}

// W[128][128] fp32 -> fragment-ordered bf16 image for MFMA "A" operand.
__global__ __launch_bounds__(256) void prep_w(
    const float* __restrict__ Wp, const float* __restrict__ Wa,
    unsigned short* __restrict__ WtP, unsigned short* __restrict__ WtA)
{
  const float* W = blockIdx.x ? Wa : Wp;
  unsigned short* Wt = blockIdx.x ? WtA : WtP;
  int t = threadIdx.x;
#pragma unroll
  for (int i = 0; i < 8; ++i) {
    int idx = i * 256 + t;          // 0..2047
    int f = idx >> 6;
    int lane = idx & 63;
    int tt = f >> 2, ks = f & 3;
    int m = lane & 15, q = lane >> 4;
    int col = tt * 16 + m;
    int kb = ks * 32 + q * 8;
    ushort8 h;
#pragma unroll
    for (int j = 0; j < 8; ++j) h[j] = f32_to_bf16(W[(size_t)(kb + j) * HID + col]);
    *(ushort8*)&Wt[(size_t)idx * 8] = h;
  }
}

// Y[M,128](bf16) = rowscale(X[M,128]) @ W[128,128] + bias
// Barrier-free reg-resident MFMA, software-pipelined next-tile X prefetch,
// exact-fit persistent grid, LDS-transposed full-line stores.
template<bool X_IS_BF16>
__global__ __launch_bounds__(256, 3) void gemm_mfma(
    const void* __restrict__ Xv, const unsigned short* __restrict__ Wfrag,
    const float* __restrict__ bias, const int* __restrict__ counts,
    unsigned short* __restrict__ Y, int M, int nTiles, int tpb)
{
  __shared__ unsigned short Bs[32 * 64 * 8];        // 32 KB W fragments
  __shared__ unsigned short Obuf[4 * 16 * OSTRIDE]; // 4 waves x 16 rows x 272B
  const int t = threadIdx.x;
#pragma unroll
  for (int i = 0; i < 8; ++i) {
    int g = i * 256 + t;
    *(ushort8*)&Bs[(size_t)g * 8] = *(const ushort8*)&Wfrag[(size_t)g * 8];
  }
  __syncthreads();

  const int w = t >> 6;
  const int lane = t & 63;
  const int m = lane & 15;
  const int q = lane >> 4;
  unsigned short* ob = &Obuf[w * 16 * OSTRIDE];

  const int t0 = blockIdx.x * tpb;
  const int t1 = min(t0 + tpb, nTiles);

  int tile = t0 + w;
  if (tile >= t1) return;

  auto loadraw = [&](int tl, floatx4* rf, short8* rs) {
    const int p = tl * 16 + m;
    const bool v = (p < M);
    if constexpr (X_IS_BF16) {
      const unsigned short* X = (const unsigned short*)Xv;
      const unsigned short* xp = X + (size_t)p * HID + q * 8;
#pragma unroll
      for (int ks = 0; ks < 4; ++ks)
        rs[ks] = v ? *(const short8*)(xp + ks * 32) : (short8)0;
    } else {
      const float* X = (const float*)Xv;
      const float* xp = X + (size_t)p * HID + q * 8;
#pragma unroll
      for (int ks = 0; ks < 4; ++ks) {
        rf[2 * ks]     = v ? __builtin_nontemporal_load((const floatx4*)(xp + ks * 32))     : (floatx4)(0.f);
        rf[2 * ks + 1] = v ? __builtin_nontemporal_load((const floatx4*)(xp + ks * 32 + 4)) : (floatx4)(0.f);
      }
    }
  };

  auto compute_store = [&](int tl, const floatx4* rf, const short8* rs) {
    short8 xf[4];
    if constexpr (X_IS_BF16) {
#pragma unroll
      for (int ks = 0; ks < 4; ++ks) xf[ks] = rs[ks];
    } else {
#pragma unroll
      for (int ks = 0; ks < 4; ++ks) {
        short8 h;
        h[0] = (short)f32_to_bf16(rf[2*ks][0]); h[1] = (short)f32_to_bf16(rf[2*ks][1]);
        h[2] = (short)f32_to_bf16(rf[2*ks][2]); h[3] = (short)f32_to_bf16(rf[2*ks][3]);
        h[4] = (short)f32_to_bf16(rf[2*ks+1][0]); h[5] = (short)f32_to_bf16(rf[2*ks+1][1]);
        h[6] = (short)f32_to_bf16(rf[2*ks+1][2]); h[7] = (short)f32_to_bf16(rf[2*ks+1][3]);
        xf[ks] = h;
      }
    }

    floatx4 acc[8];
#pragma unroll
    for (int tt = 0; tt < 8; ++tt) acc[tt] = (floatx4)(0.f);
#pragma unroll
    for (int ks = 0; ks < 4; ++ks) {
#pragma unroll
      for (int tt = 0; tt < 8; ++tt) {
        short8 wf = *(const short8*)&Bs[(size_t)((tt * 4 + ks) * 64 + lane) * 8];
        acc[tt] = __builtin_amdgcn_mfma_f32_16x16x32_bf16(wf, xf[ks], acc[tt], 0, 0, 0);
      }
    }

    const int p = tl * 16 + m;
    const bool valid = (p < M);
    float inv = 1.0f;
    if (counts) {
      float c = valid ? (float)counts[p] : 1.0f;
      inv = 1.0f / fmaxf(c, 1.0f);
    }

#pragma unroll
    for (int tt = 0; tt < 8; ++tt) {
      const float4 bv = *(const float4*)(bias + tt * 16 + q * 4);
      ushort4_t o;
      o[0] = f32_to_bf16(acc[tt][0] * inv + bv.x);
      o[1] = f32_to_bf16(acc[tt][1] * inv + bv.y);
      o[2] = f32_to_bf16(acc[tt][2] * inv + bv.z);
      o[3] = f32_to_bf16(acc[tt][3] * inv + bv.w);
      *(ushort4_t*)&ob[m * OSTRIDE + tt * 16 + q * 4] = o;
    }
    asm volatile("s_waitcnt lgkmcnt(0)" ::: "memory");

    {
      const int r = lane & 15;
      const int c = lane >> 4;
      const int row = tl * 16 + r;
#pragma unroll
      for (int j = 0; j < 4; ++j) {
        ushort8 vv = *(const ushort8*)&ob[r * OSTRIDE + j * 32 + c * 8];
        if (row < M)
          *(ushort8*)(Y + (size_t)row * HID + j * 32 + c * 8) = vv;
      }
    }
    asm volatile("s_waitcnt lgkmcnt(0)" ::: "memory");
  };

  floatx4 rfA[8], rfB[8];
  short8  rsA[4], rsB[4];
  loadraw(tile, rfA, rsA);
  while (true) {
    int nA = tile + 4;
    if (nA < t1) loadraw(nA, rfB, rsB);   // prefetch under MFMA below
    compute_store(tile, rfA, rsA);
    tile = nA;
    if (tile >= t1) break;
    int nB = tile + 4;
    if (nB < t1) loadraw(nB, rfA, rsA);
    compute_store(tile, rfB, rsB);
    tile = nB;
    if (tile >= t1) break;
  }
}

// ---- bucket-level histogram + scan ----
__global__ __launch_bounds__(256) void bucket_hist(
    const int* __restrict__ aid, int* __restrict__ bcnt, int n)
{
  __shared__ int hist[NB];
  int t = threadIdx.x;
  for (int i = t; i < NB; i += 256) hist[i] = 0;
  __syncthreads();
  int e0 = blockIdx.x * CHUNK;
  int e1 = min(e0 + CHUNK, n);
  for (int e = e0 + t; e < e1; e += 256) atomicAdd(&hist[aid[e] >> ABITS], 1);
  __syncthreads();
  for (int i = t; i < NB; i += 256) {
    int h = hist[i];
    if (h) atomicAdd(&bcnt[i], h);
  }
}

__global__ __launch_bounds__(512) void bucket_scan(
    const int* __restrict__ bcnt, int* __restrict__ boff, int* __restrict__ bcur, int n)
{
  __shared__ int s[512];
  int t = threadIdx.x;
  int v = (t < NB) ? bcnt[t] : 0;
  s[t] = v; __syncthreads();
#pragma unroll
  for (int off = 1; off < 512; off <<= 1) {
    int tv = 0;
    if (t >= off) tv = s[t - off];
    __syncthreads();
    if (t >= off) s[t] += tv;
    __syncthreads();
  }
  if (t < NB) { int e = s[t] - v; boff[t] = e; bcur[t] = e; }
  if (t == 0) boff[NB] = n;
}

// partition (aid,pid) pairs bucket-major; LDS-binned
__global__ __launch_bounds__(256) void partA(
    const int* __restrict__ aid, const int* __restrict__ pid,
    int* __restrict__ bcur, uint2* __restrict__ pairs, int n)
{
  __shared__ int hist[NB];
  __shared__ int cur[NB];
  int t = threadIdx.x;
  for (int i = t; i < NB; i += 256) hist[i] = 0;
  __syncthreads();
  int e0 = blockIdx.x * CHUNK;
  int e1 = min(e0 + CHUNK, n);
  for (int e = e0 + t; e < e1; e += 256) atomicAdd(&hist[aid[e] >> ABITS], 1);
  __syncthreads();
  for (int i = t; i < NB; i += 256) {
    int h = hist[i];
    cur[i] = h ? atomicAdd(&bcur[i], h) : 0;
  }
  __syncthreads();
  for (int e = e0 + t; e < e1; e += 256) {
    int a = aid[e];
    int pos = atomicAdd(&cur[a >> ABITS], 1);
    pairs[pos] = make_uint2((unsigned)a, (unsigned)pid[e]);
  }
}

// one block per bucket: count + LDS-scan its 512 authors (emits offsets/cnt),
// then scatter pids into this bucket's csr window. Replaces hist+scan1+scan3b.
__global__ __launch_bounds__(256) void partB2(
    const uint2* __restrict__ pairs, const int* __restrict__ boff,
    int* __restrict__ offsets, int* __restrict__ cnt, int* __restrict__ csr)
{
  __shared__ int lcnt[1 << ABITS];
  __shared__ int lscan[256];
  __shared__ int lcur[1 << ABITS];
  const int b = blockIdx.x;
  const int t = threadIdx.x;
  const int a0 = b << ABITS;
  lcnt[t] = 0; lcnt[t + 256] = 0;
  __syncthreads();
  const int s = boff[b], e = boff[b + 1];
  for (int i = s + t; i < e; i += 256) atomicAdd(&lcnt[pairs[i].x - a0], 1);
  __syncthreads();
  // exclusive scan of 512 counters: pair-sum then 256-wide Hillis-Steele
  const int c0 = lcnt[2 * t], c1 = lcnt[2 * t + 1];
  const int v = c0 + c1;
  lscan[t] = v; __syncthreads();
#pragma unroll
  for (int off = 1; off < 256; off <<= 1) {
    int tv = 0;
    if (t >= off) tv = lscan[t - off];
    __syncthreads();
    if (t >= off) lscan[t] += tv;
    __syncthreads();
  }
  const int ex = lscan[t] - v;
  const int o0 = s + ex, o1 = o0 + c0;
  lcur[2 * t] = o0; lcur[2 * t + 1] = o1;
  const int g0 = a0 + 2 * t, g1 = g0 + 1;
  if (g0 < NUM_AUTHORS) { offsets[g0] = o0; cnt[g0] = c0; }
  if (g1 < NUM_AUTHORS) { offsets[g1] = o1; cnt[g1] = c1; }
  __syncthreads();
  for (int i = s + t; i < e; i += 256) {
    uint2 pr = pairs[i];
    int pos = atomicAdd(&lcur[pr.x - a0], 1);
    csr[pos] = (int)pr.y;
  }
}

// One 16-lane group per author; vector csr read + shfl broadcast; 4 gathers in flight.
__global__ __launch_bounds__(256) void accumulate_kernel(
    const unsigned short* __restrict__ paper_hb, const int* __restrict__ csr,
    const int* __restrict__ offsets, const int* __restrict__ cnt,
    unsigned short* __restrict__ author_in)
{
  const int a = (blockIdx.x * 256 + threadIdx.x) >> 4;
  if (a >= NUM_AUTHORS) return;
  const int c16 = threadIdx.x & 15;
  const int start = offsets[a];
  const int n = cnt[a];
  float acc[8];
#pragma unroll
  for (int j = 0; j < 8; ++j) acc[j] = 0.f;
  for (int i = 0; i < n; i += 16) {
    const int rem = n - i;
    int idxv = (c16 < rem) ? csr[start + i + c16] : 0;
#pragma unroll
    for (int j0 = 0; j0 < 16; j0 += 4) {
      if (j0 < rem) {
        int p0 = __shfl(idxv, j0 + 0, 16);
        int p1 = __shfl(idxv, j0 + 1, 16);
        int p2 = __shfl(idxv, j0 + 2, 16);
        int p3 = __shfl(idxv, j0 + 3, 16);
        bool v1 = (j0 + 1) < rem, v2 = (j0 + 2) < rem, v3 = (j0 + 3) < rem;
        ushort8 h0, h1, h2, h3;
        h0 = *(const ushort8*)(paper_hb + (size_t)p0 * HID + c16 * 8);
        if (v1) h1 = *(const ushort8*)(paper_hb + (size_t)p1 * HID + c16 * 8);
        if (v2) h2 = *(const ushort8*)(paper_hb + (size_t)p2 * HID + c16 * 8);
        if (v3) h3 = *(const ushort8*)(paper_hb + (size_t)p3 * HID + c16 * 8);
#pragma unroll
        for (int j = 0; j < 8; ++j) acc[j] += bf16_to_f32(h0[j]);
        if (v1) {
#pragma unroll
          for (int j = 0; j < 8; ++j) acc[j] += bf16_to_f32(h1[j]);
        }
        if (v2) {
#pragma unroll
          for (int j = 0; j < 8; ++j) acc[j] += bf16_to_f32(h2[j]);
        }
        if (v3) {
#pragma unroll
          for (int j = 0; j < 8; ++j) acc[j] += bf16_to_f32(h3[j]);
        }
      }
    }
  }
  ushort8 o;
#pragma unroll
  for (int j = 0; j < 8; ++j) o[j] = f32_to_bf16(acc[j]);
  *(ushort8*)(author_in + (size_t)a * HID + c16 * 8) = o;
}

// Two edges per 16-lane group; 4 row-gathers in flight.
__global__ __launch_bounds__(256) void dot_kernel(
    const unsigned short* __restrict__ author_hb, const unsigned short* __restrict__ paper_hb,
    const int* __restrict__ la, const int* __restrict__ lp,
    float* __restrict__ out, int n)
{
  const int g = blockIdx.x * 16 + (threadIdx.x >> 4);
  const int e0 = 2 * g, e1 = e0 + 1;
  if (e0 >= n) return;
  const int c16 = threadIdx.x & 15;
  const bool has1 = (e1 < n);
  int a0i = la[e0], p0i = lp[e0];
  int a1i = has1 ? la[e1] : a0i;
  int p1i = has1 ? lp[e1] : p0i;
  ushort8 ah0 = *(const ushort8*)(author_hb + (size_t)a0i * HID + c16 * 8);
  ushort8 ph0 = *(const ushort8*)(paper_hb  + (size_t)p0i * HID + c16 * 8);
  ushort8 ah1 = *(const ushort8*)(author_hb + (size_t)a1i * HID + c16 * 8);
  ushort8 ph1 = *(const ushort8*)(paper_hb  + (size_t)p1i * HID + c16 * 8);
  float s0 = 0.f, s1 = 0.f;
#pragma unroll
  for (int j = 0; j < 8; ++j) {
    s0 += bf16_to_f32(ah0[j]) * bf16_to_f32(ph0[j]);
    s1 += bf16_to_f32(ah1[j]) * bf16_to_f32(ph1[j]);
  }
#pragma unroll
  for (int off = 1; off < 16; off <<= 1) {
    s0 += __shfl_xor(s0, off, 64);
    s1 += __shfl_xor(s1, off, 64);
  }
  if (c16 == 0) {
    __builtin_nontemporal_store(s0, &out[e0]);
    if (has1) __builtin_nontemporal_store(s1, &out[e1]);
  }
}

extern "C" void kernel_launch(void* const* d_in, const int* in_sizes, int n_in,
                              void* d_out, int out_size, void* d_ws, size_t ws_size,
                              hipStream_t stream)
{
  const float* paper_x          = (const float*)d_in[0];
  const int*   author_ids       = (const int*)d_in[1];
  const int*   paper_ids        = (const int*)d_in[2];
  const int*   label_author_ids = (const int*)d_in[3];
  const int*   label_paper_ids  = (const int*)d_in[4];
  const float* W_paper          = (const float*)d_in[5];
  const float* b_paper          = (const float*)d_in[6];
  const float* W_author         = (const float*)d_in[7];
  const float* b_author         = (const float*)d_in[8];
  float* out = (float*)d_out;

  const int num_papers = in_sizes[0] / HID;
  const int num_edges  = in_sizes[1];
  const int num_label  = in_sizes[3];
  const int NA = NUM_AUTHORS;

  char* ws = (char*)d_ws;
  size_t off = 0;
  auto alloc = [&](size_t bytes) { void* p = ws + off; off = (off + bytes + 255) & ~(size_t)255; return p; };
  unsigned short* paper_hb  = (unsigned short*)alloc((size_t)num_papers * HID * 2);
  unsigned short* author_in = (unsigned short*)alloc((size_t)NA * HID * 2);
  unsigned short* author_hb = (unsigned short*)alloc((size_t)NA * HID * 2);
  int* counts_int = (int*)alloc((size_t)NA * 4);
  int* bcnt       = (int*)alloc((size_t)(NB + 1) * 4);
  int* boff       = (int*)alloc((size_t)(NB + 1) * 4);
  int* bcur       = (int*)alloc((size_t)NB * 4);
  int* offsets    = (int*)alloc((size_t)NA * 4);
  int* csr        = (int*)alloc((size_t)num_edges * 4);
  uint2* pairs    = (uint2*)alloc((size_t)num_edges * 8);
  unsigned short* WtP = (unsigned short*)alloc(HID * HID * 2);
  unsigned short* WtA = (unsigned short*)alloc(HID * HID * 2);

  hipMemsetAsync(bcnt, 0, (size_t)(NB + 1) * 4, stream);

  prep_w<<<2, 256, 0, stream>>>(W_paper, W_author, WtP, WtA);

  // paper GEMM: exact-fit persistent grid (<=768 blocks = 3/CU), contiguous ranges
  {
    const int nTiles = (num_papers + 15) / 16;
    int tpb = (nTiles + 767) / 768;
    int blocks = (nTiles + tpb - 1) / tpb;
    gemm_mfma<false><<<blocks, 256, 0, stream>>>(
        paper_x, WtP, b_paper, nullptr, paper_hb, num_papers, nTiles, tpb);
  }

  const int nchunks = (num_edges + CHUNK - 1) / CHUNK;
  bucket_hist<<<nchunks, 256, 0, stream>>>(author_ids, bcnt, num_edges);
  bucket_scan<<<1, 512, 0, stream>>>(bcnt, boff, bcur, num_edges);
  partA<<<nchunks, 256, 0, stream>>>(author_ids, paper_ids, bcur, pairs, num_edges);
  partB2<<<NB, 256, 0, stream>>>(pairs, boff, offsets, counts_int, csr);

  accumulate_kernel<<<(NA + 15) / 16, 256, 0, stream>>>(
      paper_hb, csr, offsets, counts_int, author_in);

  // author GEMM
  {
    const int nTiles = (NA + 15) / 16;
    int tpb = (nTiles + 767) / 768;
    int blocks = (nTiles + tpb - 1) / tpb;
    gemm_mfma<true><<<blocks, 256, 0, stream>>>(
        author_in, WtA, b_author, counts_int, author_hb, NA, nTiles, tpb);
  }

  dot_kernel<<<(num_label + 31) / 32, 256, 0, stream>>>(
      author_hb, paper_hb, label_author_ids, label_paper_ids, out, num_label);
}